// Round 12
// baseline (254.625 us; speedup 1.0000x reference)
//
#include <hip/hip_runtime.h>
#include <hip/hip_bf16.h>
#include <hip/hip_fp16.h>
#include <math.h>

static constexpr int D  = 64;     // input dim
static constexpr int F1 = 1024;   // H1*C1
static constexpr int NTOT = 3072; // 3 fused GEMM outputs

typedef _Float16 f16x8 __attribute__((ext_vector_type(8)));  // MFMA A/B frag
typedef _Float16 h2    __attribute__((ext_vector_type(2)));  // packed pair
typedef float    f32x4 __attribute__((ext_vector_type(4)));
typedef unsigned int u32x4 __attribute__((ext_vector_type(4))); // NT-store vec

__device__ __forceinline__ float lrelu(float x) { return x > 0.f ? x : 0.2f * x; }

// dot of two f16 pairs, f32 accumulate (v_dot2_f32_f16 when available)
__device__ __forceinline__ float dot2f(h2 a, h2 b, float c) {
#if __has_builtin(__builtin_amdgcn_fdot2)
    return __builtin_amdgcn_fdot2(a, b, c, false);
#else
    return c + (float)a[0] * (float)b[0] + (float)a[1] * (float)b[1];
#endif
}

// 16-lane sum via DPP row ops (VALU pipe): xor1=0xB1, xor2=0x4E,
// xor4=row_half_mirror(0x141), xor8=row_mirror(0x140).
__device__ __forceinline__ float red16(float p) {
    int v = __builtin_bit_cast(int, p);
    p += __builtin_bit_cast(float, __builtin_amdgcn_mov_dpp(v, 0xB1, 0xF, 0xF, true));
    v = __builtin_bit_cast(int, p);
    p += __builtin_bit_cast(float, __builtin_amdgcn_mov_dpp(v, 0x4E, 0xF, 0xF, true));
    v = __builtin_bit_cast(int, p);
    p += __builtin_bit_cast(float, __builtin_amdgcn_mov_dpp(v, 0x141, 0xF, 0xF, true));
    v = __builtin_bit_cast(int, p);
    p += __builtin_bit_cast(float, __builtin_amdgcn_mov_dpp(v, 0x140, 0xF, 0xF, true));
    return p;
}

union U4H { uint4 u; h2 h[4]; };

// ------ fused prep: block-partitioned {x->f16 cast | degree count | W pack}
__global__ __launch_bounds__(256) void k_prep(
    const float* __restrict__ x, _Float16* __restrict__ xh,
    const int* __restrict__ ei, int* __restrict__ deg,
    const float* __restrict__ Wl1, const float* __restrict__ Wr1,
    const float* __restrict__ Wsk, _Float16* __restrict__ WhT,
    int n, int ne, int m, int castB, int degB)
{
    __shared__ _Float16 wt[128 * 72];
    const int b = blockIdx.x;
    if (b < castB) {
        int t = b * 256 + threadIdx.x;
        int ncast = (n * D) / 4;               // float4 chunks of x
        if (t < ncast) {
            float4 v = ((const float4*)x)[t];
            union { _Float16 h[4]; uint2 u; } o;
            o.h[0] = (_Float16)v.x; o.h[1] = (_Float16)v.y;
            o.h[2] = (_Float16)v.z; o.h[3] = (_Float16)v.w;
            *(uint2*)(xh + (size_t)t * 4) = o.u;
        }
    } else if (b < castB + degB) {
        int t = (b - castB) * 256 + threadIdx.x;
        if (t < m) {
            int d = (t < ne) ? ei[ne + t] : t - ne;
            atomicAdd(&deg[d], 1);
        }
    } else {
        // W^T pack via LDS transpose (coalesced global reads)
        const int t = threadIdx.x;
        const int c0 = (b - castB - degB) * 128;     // global col in [0,3072)
        const float* __restrict__ W = (c0 < 1024) ? Wl1 : (c0 < 2048) ? Wr1 : Wsk;
        const int cw = c0 & 1023;
#pragma unroll
        for (int q = 0; q < 8; ++q) {
            int idx = t + 256 * q;                   // 2048 float4 chunks
            int k = idx >> 5, c4 = (idx & 31) * 4;
            float4 v = *(const float4*)(W + (size_t)k * F1 + cw + c4);
            wt[(c4 + 0) * 72 + k] = (_Float16)v.x;
            wt[(c4 + 1) * 72 + k] = (_Float16)v.y;
            wt[(c4 + 2) * 72 + k] = (_Float16)v.z;
            wt[(c4 + 3) * 72 + k] = (_Float16)v.w;
        }
        __syncthreads();
#pragma unroll
        for (int q = 0; q < 4; ++q) {
            int idx = t + 256 * q;                   // 1024 chunks of 8 f16
            int c = idx >> 3, k0 = (idx & 7) * 8;
            uint4 v = *(const uint4*)(&wt[c * 72 + k0]);
            *(uint4*)(WhT + (size_t)(c0 + c) * 64 + k0) = v;
        }
    }
}

// ------------------------------------------------- exclusive scan -> rowptr
__global__ __launch_bounds__(1024) void k_scan(const int* __restrict__ deg,
                                               int* __restrict__ rowptr, int n)
{
    __shared__ int sums[1024];
    const int t = threadIdx.x;
    const int chunk = (n + 1023) / 1024;
    const int base = t * chunk;
    int s = 0;
    for (int i = 0; i < chunk; ++i) {
        int idx = base + i;
        if (idx < n) s += deg[idx];
    }
    sums[t] = s;
    __syncthreads();
    for (int off = 1; off < 1024; off <<= 1) {
        int v = (t >= off) ? sums[t - off] : 0;
        __syncthreads();
        sums[t] += v;
        __syncthreads();
    }
    int run = (t == 0) ? 0 : sums[t - 1];
    for (int i = 0; i < chunk; ++i) {
        int idx = base + i;
        if (idx < n) { rowptr[idx] = run; run += deg[idx]; }
    }
    if (t == 0) rowptr[n] = sums[1023];
}

// -------------------- fused MFMA GEMM (f16) + CSR scatter stripe
// blockIdx.y < 24: GEMM 128x128 tile. blockIdx.y == 24: grid-stride CSR
// scatter of src byte offsets (scan already done; conv1 runs after).
#define AS(r, c) smem[(r) * 72 + (c)]
#define BS(r, c) smem[128 * 72 + (r) * 72 + (c)]
#define CS(r, c) smem[(r) * 136 + (c)]
__global__ __launch_bounds__(256) void k_gemm_mfma(
    const _Float16* __restrict__ xh, const _Float16* __restrict__ WhT,
    const float* __restrict__ bl1, const float* __restrict__ br1,
    const float* __restrict__ bsk, const float* __restrict__ b1,
    _Float16* __restrict__ xl1h, _Float16* __restrict__ xr1h,
    _Float16* __restrict__ sk1h,
    const int* __restrict__ ei, const int* __restrict__ rowptr,
    int* __restrict__ cursor, int* __restrict__ csr_off,
    int n, int ne, int m)
{
    extern __shared__ _Float16 smem[];   // 36864 B dynamic
    const int t  = threadIdx.x;

    if (blockIdx.y == gridDim.y - 1) {   // ---- scatter stripe
        const int stride = gridDim.x * 256;
        for (int e = blockIdx.x * 256 + t; e < m; e += stride) {
            int s, d;
            if (e < ne) { s = ei[e]; d = ei[ne + e]; }
            else        { s = e - ne; d = s; }
            int pos = rowptr[d] + atomicAdd(&cursor[d], 1);
            csr_off[pos] = s << 11;      // byte offset into f16 row array
        }
        return;
    }

    const int r0 = blockIdx.x * 128;
    const int c0 = blockIdx.y * 128;

#pragma unroll
    for (int q = 0; q < 4; ++q) {
        int c = t + 256 * q;            // 1024 chunks of 16B
        int row = c >> 3, off = (c & 7) * 8;
        uint4 v = make_uint4(0, 0, 0, 0);
        if (r0 + row < n) v = *(const uint4*)(xh + (size_t)(r0 + row) * 64 + off);
        *(uint4*)(&AS(row, off)) = v;
        uint4 w = *(const uint4*)(WhT + (size_t)(c0 + row) * 64 + off);
        *(uint4*)(&BS(row, off)) = w;
    }
    __syncthreads();

    const int wave = t >> 6, lane = t & 63;
    const int quad = lane >> 4, l16 = lane & 15;
    const int mw = (wave & 1) * 64, nw = (wave >> 1) * 64;

    f16x8 bfrag[4][2];
#pragma unroll
    for (int nt = 0; nt < 4; ++nt)
#pragma unroll
        for (int ks = 0; ks < 2; ++ks)
            bfrag[nt][ks] = *(const f16x8*)(&BS(nw + nt * 16 + l16, ks * 32 + quad * 8));

    f32x4 acc[4][4];
#pragma unroll
    for (int mt = 0; mt < 4; ++mt)
#pragma unroll
        for (int nt = 0; nt < 4; ++nt) acc[mt][nt] = (f32x4){0.f, 0.f, 0.f, 0.f};

#pragma unroll
    for (int mt = 0; mt < 4; ++mt) {
        f16x8 af[2];
#pragma unroll
        for (int ks = 0; ks < 2; ++ks)
            af[ks] = *(const f16x8*)(&AS(mw + mt * 16 + l16, ks * 32 + quad * 8));
#pragma unroll
        for (int nt = 0; nt < 4; ++nt)
#pragma unroll
            for (int ks = 0; ks < 2; ++ks)
                acc[mt][nt] = __builtin_amdgcn_mfma_f32_16x16x32_f16(
                    af[ks], bfrag[nt][ks], acc[mt][nt], 0, 0, 0);
    }

    const int which = c0 >> 10;                 // 0:xl 1:xr 2:skip
    const int csec  = c0 & 1023;
    __syncthreads();
#pragma unroll
    for (int nt = 0; nt < 4; ++nt) {
        int col = csec + nw + nt * 16 + l16;
        float bias = (which == 0) ? bl1[col] : (which == 1) ? br1[col]
                                             : (bsk[col] + b1[col]);
#pragma unroll
        for (int mt = 0; mt < 4; ++mt) {
#pragma unroll
            for (int r = 0; r < 4; ++r)
                CS(mw + mt * 16 + quad * 4 + r, nw + nt * 16 + l16) =
                    (_Float16)(acc[mt][nt][r] + bias);
        }
    }
    __syncthreads();

    _Float16* __restrict__ dst = (which == 0) ? xl1h : (which == 1) ? xr1h : sk1h;
#pragma unroll
    for (int it = 0; it < 8; ++it) {
        int idx = t + 256 * it;                 // 2048 chunks of 8 halfs
        int row = idx >> 4, c16 = idx & 15;
        int grow = r0 + row;
        if (grow < n) {
            u32x4 v = *(u32x4*)(&CS(row, c16 * 8));
            __builtin_nontemporal_store(v,
                (u32x4*)(dst + (size_t)grow * F1 + csec + c16 * 8));
        }
    }
}

// ------- conv1 agg + softmax + skip + LayerNorm + ELU + conv2 proj (fused)
// TWO waves per destination node (feature half q each). Lane handles 8 cols
// at q*512 + lane*8 (16 B/edge); head = lane/16 -> DPP red16. Ping-pong
// 4-edge chunks: 4 gathers in flight, 4 independent reduce chains per chunk.
__global__ __launch_bounds__(256, 4) void k_conv1_ln(
    const int* __restrict__ rowptr, const int* __restrict__ csr_off,
    const _Float16* __restrict__ xl1h, const _Float16* __restrict__ xr1h,
    const _Float16* __restrict__ sk1h,
    const float* __restrict__ att1,
    const float* __restrict__ g1, const float* __restrict__ beta1,
    const float* __restrict__ Wl2, const float* __restrict__ bl2,
    const float* __restrict__ Wr2, const float* __restrict__ br2,
    float* __restrict__ xl2, float* __restrict__ xr2, int n)
{
    __shared__ float sb[2][2][6];
    const int slot = threadIdx.x >> 7;          // node within block
    const int q    = (threadIdx.x >> 6) & 1;    // feature half
    const int lane = threadIdx.x & 63;
    const int node = blockIdx.x * 2 + slot;
    const bool active = node < n;
    const int cb  = q * 512 + lane * 8;
    const int cbB = cb * 2;                     // byte offset within row
    const h2 c02 = (h2){(_Float16)0.2f, (_Float16)0.2f};
    const char* __restrict__ xlB = (const char*)xl1h;

    h2 xrv[4], at2[4], O[4];
    float ll = 0.f;
    float v[8];
    float s1 = 0.f, s2 = 0.f;

    if (active) {
        U4H u; u.u = *(const uint4*)(xr1h + (size_t)node * F1 + cb);
#pragma unroll
        for (int j = 0; j < 4; ++j) xrv[j] = u.h[j];
        float4 a0 = *(const float4*)(att1 + cb);
        float4 a1 = *(const float4*)(att1 + cb + 4);
        at2[0] = (h2){(_Float16)a0.x, (_Float16)a0.y};
        at2[1] = (h2){(_Float16)a0.z, (_Float16)a0.w};
        at2[2] = (h2){(_Float16)a1.x, (_Float16)a1.y};
        at2[3] = (h2){(_Float16)a1.z, (_Float16)a1.w};
#pragma unroll
        for (int j = 0; j < 4; ++j) O[j] = (h2){(_Float16)0.f, (_Float16)0.f};

        const int beg = rowptr[node], end = rowptr[node + 1];

        // load a 4-edge chunk (indices clamped; degree >= 1 via self loop)
        auto load4 = [&](U4H* buf, int base) {
#pragma unroll
            for (int k = 0; k < 4; ++k) {
                int idx = base + k;
                idx = idx < end ? idx : end - 1;
                buf[k].u = *(const uint4*)(xlB + (size_t)(unsigned)csr_off[idx] + cbB);
            }
        };
        // process a 4-edge chunk: 4 independent logit chains, then accumulate
        auto proc4 = [&](const U4H* buf, int base) {
            float p[4];
#pragma unroll
            for (int k = 0; k < 4; ++k) {
                float pp = 0.f;
#pragma unroll
                for (int j = 0; j < 4; ++j) {
                    h2 s = buf[k].h[j] + xrv[j];                    // v_pk_add_f16
                    h2 r = __builtin_elementwise_max(s, s * c02);   // lrelu
                    pp = dot2f(r, at2[j], pp);                      // v_dot2_f32_f16
                }
                p[k] = pp;
            }
#pragma unroll
            for (int k = 0; k < 4; ++k) p[k] = red16(p[k]);
#pragma unroll
            for (int k = 0; k < 4; ++k) {
                float w = (base + k < end) ? __expf(p[k]) : 0.f;    // bounded logits
                ll += w;
                _Float16 wh = (_Float16)w;
                h2 wh2 = (h2){wh, wh};
#pragma unroll
                for (int j = 0; j < 4; ++j) O[j] = O[j] + wh2 * buf[k].h[j];
            }
        };

        U4H A[4], B[4];
        load4(A, beg);
        int i = beg;
        while (true) {
            bool more = (i + 4 < end);
            if (more) load4(B, i + 4);
            proc4(A, i);
            i += 4;
            if (!more) break;

            bool more2 = (i + 4 < end);
            if (more2) load4(A, i + 4);
            proc4(B, i);
            i += 4;
            if (!more2) break;
        }

        float inv = 1.f / (ll + 1e-16f);
        U4H su; su.u = *(const uint4*)(sk1h + (size_t)node * F1 + cb);
#pragma unroll
        for (int j = 0; j < 4; ++j) {
            float xv0 = (float)su.h[j][0] + (float)O[j][0] * inv;
            float xv1 = (float)su.h[j][1] + (float)O[j][1] * inv;
            v[2 * j]     = xv0;
            v[2 * j + 1] = xv1;
            s1 += xv0 + xv1;
            s2 += xv0 * xv0 + xv1 * xv1;
        }
    }
#pragma unroll
    for (int off = 32; off > 0; off >>= 1) {
        s1 += __shfl_xor(s1, off);
        s2 += __shfl_xor(s2, off);
    }
    if (lane == 0) { sb[slot][q][0] = s1; sb[slot][q][1] = s2; }
    __syncthreads();
    float mu  = (sb[slot][0][0] + sb[slot][1][0]) * (1.f / 1024.f);
    float ms  = (sb[slot][0][1] + sb[slot][1][1]) * (1.f / 1024.f);
    float var = fmaxf(ms - mu * mu, 0.f);
    float inv = rsqrtf(var + 1e-5f);

    float p0 = 0.f, p1 = 0.f, p2 = 0.f, p3 = 0.f;
    if (active) {
        float4 gA = *(const float4*)(g1 + cb),    gB = *(const float4*)(g1 + cb + 4);
        float4 bA = *(const float4*)(beta1 + cb), bB = *(const float4*)(beta1 + cb + 4);
        float gv[8] = {gA.x, gA.y, gA.z, gA.w, gB.x, gB.y, gB.z, gB.w};
        float bv[8] = {bA.x, bA.y, bA.z, bA.w, bB.x, bB.y, bB.z, bB.w};
#pragma unroll
        for (int j = 0; j < 8; j += 2) {
            float4 wl = *(const float4*)(Wl2 + (cb + j) * 2);   // rows cb+j, cb+j+1
            float4 wr = *(const float4*)(Wr2 + (cb + j) * 2);
            float y0 = (v[j]   - mu) * inv * gv[j]   + bv[j];
            float y1 = (v[j+1] - mu) * inv * gv[j+1] + bv[j+1];
            float z0 = y0 > 0.f ? y0 : __expf(y0) - 1.f;       // ELU
            float z1 = y1 > 0.f ? y1 : __expf(y1) - 1.f;
            p0 += z0 * wl.x + z1 * wl.z;
            p1 += z0 * wl.y + z1 * wl.w;
            p2 += z0 * wr.x + z1 * wr.z;
            p3 += z0 * wr.y + z1 * wr.w;
        }
    }
#pragma unroll
    for (int off = 32; off > 0; off >>= 1) {
        p0 += __shfl_xor(p0, off); p1 += __shfl_xor(p1, off);
        p2 += __shfl_xor(p2, off); p3 += __shfl_xor(p3, off);
    }
    if (lane == 0) { sb[slot][q][2] = p0; sb[slot][q][3] = p1;
                     sb[slot][q][4] = p2; sb[slot][q][5] = p3; }
    __syncthreads();
    if (active && lane == 0 && q == 0) {
        xl2[node * 2 + 0] = sb[slot][0][2] + sb[slot][1][2] + bl2[0];
        xl2[node * 2 + 1] = sb[slot][0][3] + sb[slot][1][3] + bl2[1];
        xr2[node * 2 + 0] = sb[slot][0][4] + sb[slot][1][4] + br2[0];
        xr2[node * 2 + 1] = sb[slot][0][5] + sb[slot][1][5] + br2[1];
    }
}

// ------------ conv2: fused attention + softmax + agg, 1 thread/node,
// 64-thread blocks to spread serial edge walks across all CUs.
__global__ __launch_bounds__(64) void k_conv2(
    const int* __restrict__ rowptr, const int* __restrict__ csr_off,
    const float* __restrict__ xl2, const float* __restrict__ xr2,
    const float* __restrict__ att2, const float* __restrict__ b2,
    float* __restrict__ out2, int n)
{
    int d = blockIdx.x * blockDim.x + threadIdx.x;
    if (d >= n) return;
    float2 xr = *(const float2*)(xr2 + 2 * d);
    float a0w = att2[0], a1w = att2[1];
    float m = -INFINITY, l = 0.f, o0 = 0.f, o1 = 0.f;
    const int beg = rowptr[d], end = rowptr[d + 1];
    float2 pf[2];
    pf[0] = *(const float2*)(xl2 + (csr_off[beg] >> 10));
    pf[1] = (beg + 1 < end) ? *(const float2*)(xl2 + (csr_off[beg + 1] >> 10)) : pf[0];
    for (int i = beg; i < end; ++i) {
        float2 cur = pf[0];
        pf[0] = pf[1];
        if (i + 2 < end) pf[1] = *(const float2*)(xl2 + (csr_off[i + 2] >> 10));
        float p = lrelu(cur.x + xr.x) * a0w + lrelu(cur.y + xr.y) * a1w;
        float nm = fmaxf(m, p);
        float sc = __expf(m - nm);
        float w  = __expf(p - nm);
        l = l * sc + w;
        o0 = o0 * sc + w * cur.x;
        o1 = o1 * sc + w * cur.y;
        m = nm;
    }
    float inv = 1.f / (l + 1e-16f);
    out2[2 * d + 0] = o0 * inv + b2[0];
    out2[2 * d + 1] = o1 * inv + b2[1];
}

// ----------------------------------------------------------------
extern "C" void kernel_launch(void* const* d_in, const int* in_sizes, int n_in,
                              void* d_out, int out_size, void* d_ws, size_t ws_size,
                              hipStream_t stream)
{
    const float* x     = (const float*)d_in[0];
    const int*   ei    = (const int*)  d_in[1];
    const float* Wl1   = (const float*)d_in[2];
    const float* bl1   = (const float*)d_in[3];
    const float* Wr1   = (const float*)d_in[4];
    const float* br1   = (const float*)d_in[5];
    const float* att1  = (const float*)d_in[6];
    const float* b1    = (const float*)d_in[7];
    const float* Wsk   = (const float*)d_in[8];
    const float* bsk   = (const float*)d_in[9];
    const float* g1    = (const float*)d_in[10];
    const float* beta1 = (const float*)d_in[11];
    const float* Wl2   = (const float*)d_in[12];
    const float* bl2   = (const float*)d_in[13];
    const float* Wr2   = (const float*)d_in[14];
    const float* br2   = (const float*)d_in[15];
    const float* att2  = (const float*)d_in[16];
    const float* b2    = (const float*)d_in[17];

    const int n  = in_sizes[0] / D;    // 20000
    const int ne = in_sizes[1] / 2;    // 160000
    const int m  = ne + n;             // incl. self loops

    float* ws = (float*)d_ws;
    size_t o = 0;
    _Float16* xl1h = (_Float16*)(ws + o); o += (size_t)n * F1 / 2;
    _Float16* xr1h = (_Float16*)(ws + o); o += (size_t)n * F1 / 2;
    _Float16* sk1h = (_Float16*)(ws + o); o += (size_t)n * F1 / 2;
    _Float16* xh   = (_Float16*)(ws + o); o += (size_t)n * D / 2;
    _Float16* WhT  = (_Float16*)(ws + o); o += (size_t)NTOT * 64 / 2;
    float* xl2    = ws + o; o += (size_t)n * 2;
    float* xr2    = ws + o; o += (size_t)n * 2;
    int* rowptr   = (int*)(ws + o); o += (size_t)n + 1;
    int* deg      = (int*)(ws + o); o += (size_t)n;
    int* cursor   = (int*)(ws + o); o += (size_t)n;
    int* csr_off  = (int*)(ws + o); o += (size_t)m;
    float* out2   = (float*)d_out;

    // --- graph structure + f16 prep + W pack (one fused launch) ---
    (void)hipMemsetAsync(deg, 0, (size_t)2 * n * sizeof(int), stream); // deg+cursor
    const int castB = ((n * D) / 4 + 255) / 256;   // 1250
    const int degB  = (m + 255) / 256;             // 704
    k_prep<<<castB + degB + NTOT / 128, 256, 0, stream>>>(
        x, xh, ei, deg, Wl1, Wr1, Wsk, WhT, n, ne, m, castB, degB);
    k_scan<<<1, 1024, 0, stream>>>(deg, rowptr, n);

    // --- fused MFMA GEMM + CSR scatter stripe ---
    dim3 gg((n + 127) / 128, NTOT / 128 + 1);
    k_gemm_mfma<<<gg, 256, 36864, stream>>>(xh, WhT, bl1, br1, bsk, b1,
                                            xl1h, xr1h, sk1h,
                                            ei, rowptr, cursor, csr_off,
                                            n, ne, m);

    // --- conv1 agg + LN + ELU + conv2 projections (fused, 2 waves/node) ---
    k_conv1_ln<<<(n + 1) / 2, 256, 0, stream>>>(rowptr, csr_off, xl1h, xr1h, sk1h,
                                                att1, g1, beta1, Wl2, bl2, Wr2, br2,
                                                xl2, xr2, n);

    // --- conv2 ---
    k_conv2<<<(n + 63) / 64, 64, 0, stream>>>(rowptr, csr_off, xl2, xr2, att2, b2, out2, n);
}

// Round 13
// 247.653 us; speedup vs baseline: 1.0282x; 1.0282x over previous
//
#include <hip/hip_runtime.h>
#include <hip/hip_bf16.h>
#include <hip/hip_fp16.h>
#include <math.h>

static constexpr int D  = 64;     // input dim
static constexpr int F1 = 1024;   // H1*C1
static constexpr int NTOT = 3072; // 3 fused GEMM outputs

typedef _Float16 f16x8 __attribute__((ext_vector_type(8)));  // MFMA A/B frag
typedef _Float16 h2    __attribute__((ext_vector_type(2)));  // packed pair
typedef float    f32x4 __attribute__((ext_vector_type(4)));
typedef unsigned int u32x4 __attribute__((ext_vector_type(4))); // NT-store vec

__device__ __forceinline__ float lrelu(float x) { return x > 0.f ? x : 0.2f * x; }

// dot of two f16 pairs, f32 accumulate (v_dot2_f32_f16 when available)
__device__ __forceinline__ float dot2f(h2 a, h2 b, float c) {
#if __has_builtin(__builtin_amdgcn_fdot2)
    return __builtin_amdgcn_fdot2(a, b, c, false);
#else
    return c + (float)a[0] * (float)b[0] + (float)a[1] * (float)b[1];
#endif
}

// 16-lane sum via DPP row ops (VALU pipe): xor1=0xB1, xor2=0x4E,
// xor4=row_half_mirror(0x141), xor8=row_mirror(0x140).
__device__ __forceinline__ float red16(float p) {
    int v = __builtin_bit_cast(int, p);
    p += __builtin_bit_cast(float, __builtin_amdgcn_mov_dpp(v, 0xB1, 0xF, 0xF, true));
    v = __builtin_bit_cast(int, p);
    p += __builtin_bit_cast(float, __builtin_amdgcn_mov_dpp(v, 0x4E, 0xF, 0xF, true));
    v = __builtin_bit_cast(int, p);
    p += __builtin_bit_cast(float, __builtin_amdgcn_mov_dpp(v, 0x141, 0xF, 0xF, true));
    v = __builtin_bit_cast(int, p);
    p += __builtin_bit_cast(float, __builtin_amdgcn_mov_dpp(v, 0x140, 0xF, 0xF, true));
    return p;
}

union U4H { uint4 u; h2 h[4]; };

// ------ fused prep: block-partitioned {x->f16 cast | degree count | W pack}
__global__ __launch_bounds__(256) void k_prep(
    const float* __restrict__ x, _Float16* __restrict__ xh,
    const int* __restrict__ ei, int* __restrict__ deg,
    const float* __restrict__ Wl1, const float* __restrict__ Wr1,
    const float* __restrict__ Wsk, _Float16* __restrict__ WhT,
    int n, int ne, int m, int castB, int degB)
{
    __shared__ _Float16 wt[128 * 72];
    const int b = blockIdx.x;
    if (b < castB) {
        int t = b * 256 + threadIdx.x;
        int ncast = (n * D) / 4;               // float4 chunks of x
        if (t < ncast) {
            float4 v = ((const float4*)x)[t];
            union { _Float16 h[4]; uint2 u; } o;
            o.h[0] = (_Float16)v.x; o.h[1] = (_Float16)v.y;
            o.h[2] = (_Float16)v.z; o.h[3] = (_Float16)v.w;
            *(uint2*)(xh + (size_t)t * 4) = o.u;
        }
    } else if (b < castB + degB) {
        int t = (b - castB) * 256 + threadIdx.x;
        if (t < m) {
            int d = (t < ne) ? ei[ne + t] : t - ne;
            atomicAdd(&deg[d], 1);
        }
    } else {
        // W^T pack via LDS transpose (coalesced global reads)
        const int t = threadIdx.x;
        const int c0 = (b - castB - degB) * 128;     // global col in [0,3072)
        const float* __restrict__ W = (c0 < 1024) ? Wl1 : (c0 < 2048) ? Wr1 : Wsk;
        const int cw = c0 & 1023;
#pragma unroll
        for (int q = 0; q < 8; ++q) {
            int idx = t + 256 * q;                   // 2048 float4 chunks
            int k = idx >> 5, c4 = (idx & 31) * 4;
            float4 v = *(const float4*)(W + (size_t)k * F1 + cw + c4);
            wt[(c4 + 0) * 72 + k] = (_Float16)v.x;
            wt[(c4 + 1) * 72 + k] = (_Float16)v.y;
            wt[(c4 + 2) * 72 + k] = (_Float16)v.z;
            wt[(c4 + 3) * 72 + k] = (_Float16)v.w;
        }
        __syncthreads();
#pragma unroll
        for (int q = 0; q < 4; ++q) {
            int idx = t + 256 * q;                   // 1024 chunks of 8 f16
            int c = idx >> 3, k0 = (idx & 7) * 8;
            uint4 v = *(const uint4*)(&wt[c * 72 + k0]);
            *(uint4*)(WhT + (size_t)(c0 + c) * 64 + k0) = v;
        }
    }
}

// ------------------------------------------------- exclusive scan -> rowptr
__global__ __launch_bounds__(1024) void k_scan(const int* __restrict__ deg,
                                               int* __restrict__ rowptr, int n)
{
    __shared__ int sums[1024];
    const int t = threadIdx.x;
    const int chunk = (n + 1023) / 1024;
    const int base = t * chunk;
    int s = 0;
    for (int i = 0; i < chunk; ++i) {
        int idx = base + i;
        if (idx < n) s += deg[idx];
    }
    sums[t] = s;
    __syncthreads();
    for (int off = 1; off < 1024; off <<= 1) {
        int v = (t >= off) ? sums[t - off] : 0;
        __syncthreads();
        sums[t] += v;
        __syncthreads();
    }
    int run = (t == 0) ? 0 : sums[t - 1];
    for (int i = 0; i < chunk; ++i) {
        int idx = base + i;
        if (idx < n) { rowptr[idx] = run; run += deg[idx]; }
    }
    if (t == 0) rowptr[n] = sums[1023];
}

// -------------------- fused MFMA GEMM (f16) + CSR scatter stripe
// blockIdx.y < 24: GEMM 128x128 tile. blockIdx.y == 24: grid-stride CSR
// scatter of src byte offsets (scan already done; conv1 runs after).
#define AS(r, c) smem[(r) * 72 + (c)]
#define BS(r, c) smem[128 * 72 + (r) * 72 + (c)]
#define CS(r, c) smem[(r) * 136 + (c)]
__global__ __launch_bounds__(256) void k_gemm_mfma(
    const _Float16* __restrict__ xh, const _Float16* __restrict__ WhT,
    const float* __restrict__ bl1, const float* __restrict__ br1,
    const float* __restrict__ bsk, const float* __restrict__ b1,
    _Float16* __restrict__ xl1h, _Float16* __restrict__ xr1h,
    _Float16* __restrict__ sk1h,
    const int* __restrict__ ei, const int* __restrict__ rowptr,
    int* __restrict__ cursor, int* __restrict__ csr_off,
    int n, int ne, int m)
{
    extern __shared__ _Float16 smem[];   // 36864 B dynamic
    const int t  = threadIdx.x;

    if (blockIdx.y == gridDim.y - 1) {   // ---- scatter stripe
        const int stride = gridDim.x * 256;
        for (int e = blockIdx.x * 256 + t; e < m; e += stride) {
            int s, d;
            if (e < ne) { s = ei[e]; d = ei[ne + e]; }
            else        { s = e - ne; d = s; }
            int pos = rowptr[d] + atomicAdd(&cursor[d], 1);
            csr_off[pos] = s << 11;      // byte offset into f16 row array
        }
        return;
    }

    const int r0 = blockIdx.x * 128;
    const int c0 = blockIdx.y * 128;

#pragma unroll
    for (int q = 0; q < 4; ++q) {
        int c = t + 256 * q;            // 1024 chunks of 16B
        int row = c >> 3, off = (c & 7) * 8;
        uint4 v = make_uint4(0, 0, 0, 0);
        if (r0 + row < n) v = *(const uint4*)(xh + (size_t)(r0 + row) * 64 + off);
        *(uint4*)(&AS(row, off)) = v;
        uint4 w = *(const uint4*)(WhT + (size_t)(c0 + row) * 64 + off);
        *(uint4*)(&BS(row, off)) = w;
    }
    __syncthreads();

    const int wave = t >> 6, lane = t & 63;
    const int quad = lane >> 4, l16 = lane & 15;
    const int mw = (wave & 1) * 64, nw = (wave >> 1) * 64;

    f16x8 bfrag[4][2];
#pragma unroll
    for (int nt = 0; nt < 4; ++nt)
#pragma unroll
        for (int ks = 0; ks < 2; ++ks)
            bfrag[nt][ks] = *(const f16x8*)(&BS(nw + nt * 16 + l16, ks * 32 + quad * 8));

    f32x4 acc[4][4];
#pragma unroll
    for (int mt = 0; mt < 4; ++mt)
#pragma unroll
        for (int nt = 0; nt < 4; ++nt) acc[mt][nt] = (f32x4){0.f, 0.f, 0.f, 0.f};

#pragma unroll
    for (int mt = 0; mt < 4; ++mt) {
        f16x8 af[2];
#pragma unroll
        for (int ks = 0; ks < 2; ++ks)
            af[ks] = *(const f16x8*)(&AS(mw + mt * 16 + l16, ks * 32 + quad * 8));
#pragma unroll
        for (int nt = 0; nt < 4; ++nt)
#pragma unroll
            for (int ks = 0; ks < 2; ++ks)
                acc[mt][nt] = __builtin_amdgcn_mfma_f32_16x16x32_f16(
                    af[ks], bfrag[nt][ks], acc[mt][nt], 0, 0, 0);
    }

    const int which = c0 >> 10;                 // 0:xl 1:xr 2:skip
    const int csec  = c0 & 1023;
    __syncthreads();
#pragma unroll
    for (int nt = 0; nt < 4; ++nt) {
        int col = csec + nw + nt * 16 + l16;
        float bias = (which == 0) ? bl1[col] : (which == 1) ? br1[col]
                                             : (bsk[col] + b1[col]);
#pragma unroll
        for (int mt = 0; mt < 4; ++mt) {
#pragma unroll
            for (int r = 0; r < 4; ++r)
                CS(mw + mt * 16 + quad * 4 + r, nw + nt * 16 + l16) =
                    (_Float16)(acc[mt][nt][r] + bias);
        }
    }
    __syncthreads();

    _Float16* __restrict__ dst = (which == 0) ? xl1h : (which == 1) ? xr1h : sk1h;
#pragma unroll
    for (int it = 0; it < 8; ++it) {
        int idx = t + 256 * it;                 // 2048 chunks of 8 halfs
        int row = idx >> 4, c16 = idx & 15;
        int grow = r0 + row;
        if (grow < n) {
            u32x4 v = *(u32x4*)(&CS(row, c16 * 8));
            __builtin_nontemporal_store(v,
                (u32x4*)(dst + (size_t)grow * F1 + csec + c16 * 8));
        }
    }
}

// ------- conv1 agg + softmax + skip + LayerNorm + ELU + conv2 proj (fused)
// TWO waves per destination node (feature half q each; round-8 optimum).
// Lane handles 8 cols at q*512 + lane*8 (16 B/edge); head = lane/16 -> DPP
// red16. Ping-pong 2-edge chunks; byte-offset CSR.
__global__ __launch_bounds__(256, 4) void k_conv1_ln(
    const int* __restrict__ rowptr, const int* __restrict__ csr_off,
    const _Float16* __restrict__ xl1h, const _Float16* __restrict__ xr1h,
    const _Float16* __restrict__ sk1h,
    const float* __restrict__ att1,
    const float* __restrict__ g1, const float* __restrict__ beta1,
    const float* __restrict__ Wl2, const float* __restrict__ bl2,
    const float* __restrict__ Wr2, const float* __restrict__ br2,
    float* __restrict__ xl2, float* __restrict__ xr2, int n)
{
    __shared__ float sb[2][2][6];
    const int slot = threadIdx.x >> 7;          // node within block
    const int q    = (threadIdx.x >> 6) & 1;    // feature half
    const int lane = threadIdx.x & 63;
    const int node = blockIdx.x * 2 + slot;
    const bool active = node < n;
    const int cb  = q * 512 + lane * 8;
    const int cbB = cb * 2;                     // byte offset within row
    const h2 c02 = (h2){(_Float16)0.2f, (_Float16)0.2f};
    const char* __restrict__ xlB = (const char*)xl1h;

    h2 xrv[4], at2[4], O[4];
    float ll = 0.f;
    float v[8];
    float s1 = 0.f, s2 = 0.f;

    if (active) {
        U4H u; u.u = *(const uint4*)(xr1h + (size_t)node * F1 + cb);
#pragma unroll
        for (int j = 0; j < 4; ++j) xrv[j] = u.h[j];
        float4 a0 = *(const float4*)(att1 + cb);
        float4 a1 = *(const float4*)(att1 + cb + 4);
        at2[0] = (h2){(_Float16)a0.x, (_Float16)a0.y};
        at2[1] = (h2){(_Float16)a0.z, (_Float16)a0.w};
        at2[2] = (h2){(_Float16)a1.x, (_Float16)a1.y};
        at2[3] = (h2){(_Float16)a1.z, (_Float16)a1.w};
#pragma unroll
        for (int j = 0; j < 4; ++j) O[j] = (h2){(_Float16)0.f, (_Float16)0.f};

        const int beg = rowptr[node], end = rowptr[node + 1];

        auto edge = [&](const U4H& cur, bool valid) {
            float p = 0.f;
#pragma unroll
            for (int j = 0; j < 4; ++j) {
                h2 s = cur.h[j] + xrv[j];                       // v_pk_add_f16
                h2 r = __builtin_elementwise_max(s, s * c02);   // lrelu (slope<1)
                p = dot2f(r, at2[j], p);                        // v_dot2_f32_f16
            }
            p = red16(p);                                       // DPP reduce
            float w = valid ? __expf(p) : 0.f;                  // bounded logits
            ll += w;
            _Float16 wh = (_Float16)w;
            h2 wh2 = (h2){wh, wh};
#pragma unroll
            for (int j = 0; j < 4; ++j) O[j] = O[j] + wh2 * cur.h[j];  // v_pk_fma
        };

        // ping-pong 2-edge chunks: buffers alternate roles, no rotation moves
        U4H A0, A1, B0, B1;
        {
            int i1 = (beg + 1 < end) ? beg + 1 : beg;
            A0.u = *(const uint4*)(xlB + (size_t)(unsigned)csr_off[beg] + cbB);
            A1.u = *(const uint4*)(xlB + (size_t)(unsigned)csr_off[i1]  + cbB);
        }
        int i = beg;
        while (true) {
            bool more = (i + 2 < end);
            if (more) {
                int j0 = i + 2;
                int j1 = (i + 3 < end) ? i + 3 : j0;
                B0.u = *(const uint4*)(xlB + (size_t)(unsigned)csr_off[j0] + cbB);
                B1.u = *(const uint4*)(xlB + (size_t)(unsigned)csr_off[j1] + cbB);
            }
            edge(A0, true);
            edge(A1, i + 1 < end);
            i += 2;
            if (!more) break;

            bool more2 = (i + 2 < end);
            if (more2) {
                int j0 = i + 2;
                int j1 = (i + 3 < end) ? i + 3 : j0;
                A0.u = *(const uint4*)(xlB + (size_t)(unsigned)csr_off[j0] + cbB);
                A1.u = *(const uint4*)(xlB + (size_t)(unsigned)csr_off[j1] + cbB);
            }
            edge(B0, true);
            edge(B1, i + 1 < end);
            i += 2;
            if (!more2) break;
        }

        float inv = 1.f / (ll + 1e-16f);
        U4H su; su.u = *(const uint4*)(sk1h + (size_t)node * F1 + cb);
#pragma unroll
        for (int j = 0; j < 4; ++j) {
            float xv0 = (float)su.h[j][0] + (float)O[j][0] * inv;
            float xv1 = (float)su.h[j][1] + (float)O[j][1] * inv;
            v[2 * j]     = xv0;
            v[2 * j + 1] = xv1;
            s1 += xv0 + xv1;
            s2 += xv0 * xv0 + xv1 * xv1;
        }
    }
#pragma unroll
    for (int off = 32; off > 0; off >>= 1) {
        s1 += __shfl_xor(s1, off);
        s2 += __shfl_xor(s2, off);
    }
    if (lane == 0) { sb[slot][q][0] = s1; sb[slot][q][1] = s2; }
    __syncthreads();
    float mu  = (sb[slot][0][0] + sb[slot][1][0]) * (1.f / 1024.f);
    float ms  = (sb[slot][0][1] + sb[slot][1][1]) * (1.f / 1024.f);
    float var = fmaxf(ms - mu * mu, 0.f);
    float inv = rsqrtf(var + 1e-5f);

    float p0 = 0.f, p1 = 0.f, p2 = 0.f, p3 = 0.f;
    if (active) {
        float4 gA = *(const float4*)(g1 + cb),    gB = *(const float4*)(g1 + cb + 4);
        float4 bA = *(const float4*)(beta1 + cb), bB = *(const float4*)(beta1 + cb + 4);
        float gv[8] = {gA.x, gA.y, gA.z, gA.w, gB.x, gB.y, gB.z, gB.w};
        float bv[8] = {bA.x, bA.y, bA.z, bA.w, bB.x, bB.y, bB.z, bB.w};
#pragma unroll
        for (int j = 0; j < 8; j += 2) {
            float4 wl = *(const float4*)(Wl2 + (cb + j) * 2);   // rows cb+j, cb+j+1
            float4 wr = *(const float4*)(Wr2 + (cb + j) * 2);
            float y0 = (v[j]   - mu) * inv * gv[j]   + bv[j];
            float y1 = (v[j+1] - mu) * inv * gv[j+1] + bv[j+1];
            float z0 = y0 > 0.f ? y0 : __expf(y0) - 1.f;       // ELU
            float z1 = y1 > 0.f ? y1 : __expf(y1) - 1.f;
            p0 += z0 * wl.x + z1 * wl.z;
            p1 += z0 * wl.y + z1 * wl.w;
            p2 += z0 * wr.x + z1 * wr.z;
            p3 += z0 * wr.y + z1 * wr.w;
        }
    }
#pragma unroll
    for (int off = 32; off > 0; off >>= 1) {
        p0 += __shfl_xor(p0, off); p1 += __shfl_xor(p1, off);
        p2 += __shfl_xor(p2, off); p3 += __shfl_xor(p3, off);
    }
    if (lane == 0) { sb[slot][q][2] = p0; sb[slot][q][3] = p1;
                     sb[slot][q][4] = p2; sb[slot][q][5] = p3; }
    __syncthreads();
    if (active && lane == 0 && q == 0) {
        xl2[node * 2 + 0] = sb[slot][0][2] + sb[slot][1][2] + bl2[0];
        xl2[node * 2 + 1] = sb[slot][0][3] + sb[slot][1][3] + bl2[1];
        xr2[node * 2 + 0] = sb[slot][0][4] + sb[slot][1][4] + br2[0];
        xr2[node * 2 + 1] = sb[slot][0][5] + sb[slot][1][5] + br2[1];
    }
}

// ------------ conv2: fused attention + softmax + agg, 1 thread/node,
// 64-thread blocks to spread serial edge walks across all CUs.
__global__ __launch_bounds__(64) void k_conv2(
    const int* __restrict__ rowptr, const int* __restrict__ csr_off,
    const float* __restrict__ xl2, const float* __restrict__ xr2,
    const float* __restrict__ att2, const float* __restrict__ b2,
    float* __restrict__ out2, int n)
{
    int d = blockIdx.x * blockDim.x + threadIdx.x;
    if (d >= n) return;
    float2 xr = *(const float2*)(xr2 + 2 * d);
    float a0w = att2[0], a1w = att2[1];
    float m = -INFINITY, l = 0.f, o0 = 0.f, o1 = 0.f;
    const int beg = rowptr[d], end = rowptr[d + 1];
    float2 pf[2];
    pf[0] = *(const float2*)(xl2 + (csr_off[beg] >> 10));
    pf[1] = (beg + 1 < end) ? *(const float2*)(xl2 + (csr_off[beg + 1] >> 10)) : pf[0];
    for (int i = beg; i < end; ++i) {
        float2 cur = pf[0];
        pf[0] = pf[1];
        if (i + 2 < end) pf[1] = *(const float2*)(xl2 + (csr_off[i + 2] >> 10));
        float p = lrelu(cur.x + xr.x) * a0w + lrelu(cur.y + xr.y) * a1w;
        float nm = fmaxf(m, p);
        float sc = __expf(m - nm);
        float w  = __expf(p - nm);
        l = l * sc + w;
        o0 = o0 * sc + w * cur.x;
        o1 = o1 * sc + w * cur.y;
        m = nm;
    }
    float inv = 1.f / (l + 1e-16f);
    out2[2 * d + 0] = o0 * inv + b2[0];
    out2[2 * d + 1] = o1 * inv + b2[1];
}

// ----------------------------------------------------------------
extern "C" void kernel_launch(void* const* d_in, const int* in_sizes, int n_in,
                              void* d_out, int out_size, void* d_ws, size_t ws_size,
                              hipStream_t stream)
{
    const float* x     = (const float*)d_in[0];
    const int*   ei    = (const int*)  d_in[1];
    const float* Wl1   = (const float*)d_in[2];
    const float* bl1   = (const float*)d_in[3];
    const float* Wr1   = (const float*)d_in[4];
    const float* br1   = (const float*)d_in[5];
    const float* att1  = (const float*)d_in[6];
    const float* b1    = (const float*)d_in[7];
    const float* Wsk   = (const float*)d_in[8];
    const float* bsk   = (const float*)d_in[9];
    const float* g1    = (const float*)d_in[10];
    const float* beta1 = (const float*)d_in[11];
    const float* Wl2   = (const float*)d_in[12];
    const float* bl2   = (const float*)d_in[13];
    const float* Wr2   = (const float*)d_in[14];
    const float* br2   = (const float*)d_in[15];
    const float* att2  = (const float*)d_in[16];
    const float* b2    = (const float*)d_in[17];

    const int n  = in_sizes[0] / D;    // 20000
    const int ne = in_sizes[1] / 2;    // 160000
    const int m  = ne + n;             // incl. self loops

    float* ws = (float*)d_ws;
    size_t o = 0;
    _Float16* xl1h = (_Float16*)(ws + o); o += (size_t)n * F1 / 2;
    _Float16* xr1h = (_Float16*)(ws + o); o += (size_t)n * F1 / 2;
    _Float16* sk1h = (_Float16*)(ws + o); o += (size_t)n * F1 / 2;
    _Float16* xh   = (_Float16*)(ws + o); o += (size_t)n * D / 2;
    _Float16* WhT  = (_Float16*)(ws + o); o += (size_t)NTOT * 64 / 2;
    float* xl2    = ws + o; o += (size_t)n * 2;
    float* xr2    = ws + o; o += (size_t)n * 2;
    int* rowptr   = (int*)(ws + o); o += (size_t)n + 1;
    int* deg      = (int*)(ws + o); o += (size_t)n;
    int* cursor   = (int*)(ws + o); o += (size_t)n;
    int* csr_off  = (int*)(ws + o); o += (size_t)m;
    float* out2   = (float*)d_out;

    // --- graph structure + f16 prep + W pack (one fused launch) ---
    (void)hipMemsetAsync(deg, 0, (size_t)2 * n * sizeof(int), stream); // deg+cursor
    const int castB = ((n * D) / 4 + 255) / 256;   // 1250
    const int degB  = (m + 255) / 256;             // 704
    k_prep<<<castB + degB + NTOT / 128, 256, 0, stream>>>(
        x, xh, ei, deg, Wl1, Wr1, Wsk, WhT, n, ne, m, castB, degB);
    k_scan<<<1, 1024, 0, stream>>>(deg, rowptr, n);

    // --- fused MFMA GEMM + CSR scatter stripe ---
    dim3 gg((n + 127) / 128, NTOT / 128 + 1);
    k_gemm_mfma<<<gg, 256, 36864, stream>>>(xh, WhT, bl1, br1, bsk, b1,
                                            xl1h, xr1h, sk1h,
                                            ei, rowptr, cursor, csr_off,
                                            n, ne, m);

    // --- conv1 agg + LN + ELU + conv2 projections (fused, 2 waves/node) ---
    k_conv1_ln<<<(n + 1) / 2, 256, 0, stream>>>(rowptr, csr_off, xl1h, xr1h, sk1h,
                                                att1, g1, beta1, Wl2, bl2, Wr2, br2,
                                                xl2, xr2, n);

    // --- conv2 ---
    k_conv2<<<(n + 63) / 64, 64, 0, stream>>>(rowptr, csr_off, xl2, xr2, att2, b2, out2, n);
}